// Round 11
// baseline (82719.244 us; speedup 1.0000x reference)
//
#include <hip/hip_runtime.h>
#include <math.h>

#define NLFULL 504
#define REAL_NL 500
#define BATCH 2048
#define NZ 50
#define NC 21
#define GHID 512
#define EPSB 1e-5f
#define LO_SCALE 2048.0f
#define INV_LO (1.0f / 2048.0f)
#define ROWS 32

typedef __attribute__((ext_vector_type(4))) float f32x4;
typedef __attribute__((ext_vector_type(8))) _Float16 half8;

__device__ __forceinline__ void split2(float x, _Float16& hi, _Float16& lo) {
    hi = (_Float16)x;
    lo = (_Float16)((x - (float)hi) * LO_SCALE);
}

// =============================== upsample ==================================
__global__ __launch_bounds__(512) void upsample_kernel(
    const float* __restrict__ z, const float* __restrict__ dW, const float* __restrict__ db,
    const float* __restrict__ W0, const float* __restrict__ g0, const float* __restrict__ bb0,
    const float* __restrict__ m0, const float* __restrict__ v0, const float* __restrict__ al0,
    const float* __restrict__ W1, const float* __restrict__ g1, const float* __restrict__ bb1,
    const float* __restrict__ m1, const float* __restrict__ v1, const float* __restrict__ al1,
    const float* __restrict__ W2, const float* __restrict__ g2, const float* __restrict__ bb2,
    const float* __restrict__ m2, const float* __restrict__ v2, const float* __restrict__ al2,
    float* __restrict__ hseq)
{
    __shared__ float bufA[5712];
    __shared__ float bufB[5544];
    __shared__ float zl[52];

    const int b   = blockIdx.x;
    const int ta  = blockIdx.y * 16;
    const int nt0 = min(16, 63 - ta);
    const int tid = threadIdx.x;

    if (tid < NZ) zl[tid] = z[b * NZ + tid];
    __syncthreads();

    for (int i = tid; i < 336 * nt0; i += 512) {
        int c = i % 336, tt = i / 336;
        int row = c * 63 + ta + tt;
        const float* wr = dW + (size_t)row * NZ;
        float s = db[row];
        #pragma unroll
        for (int n = 0; n < NZ; ++n) s += zl[n] * wr[n];
        bufA[c * 17 + tt] = s;
    }
    __syncthreads();

    const float a0 = al0[0], a1 = al1[0], a2 = al2[0];

    for (int i = tid; i < 168 * 2 * nt0; i += 512) {
        int o = i % 168, tt1 = i / 168;
        int tt = tt1 >> 1, k = tt1 & 1;
        const float* wp = W0 + o * 2 + k;
        float s = 0.f;
        for (int c = 0; c < 336; ++c) s += bufA[c * 17 + tt] * wp[c * 336];
        float sc = g0[o] / sqrtf(v0[o] + EPSB);
        s = (s - m0[o]) * sc + bb0[o];
        s = (s >= 0.f) ? s : a0 * s;
        bufB[o * 33 + tt1] = s;
    }
    __syncthreads();

    for (int i = tid; i < 84 * 4 * nt0; i += 512) {
        int o = i % 84, tt2 = i / 84;
        int tt1 = tt2 >> 1, k = tt2 & 1;
        const float* wp = W1 + o * 2 + k;
        float s = 0.f;
        for (int c = 0; c < 168; ++c) s += bufB[c * 33 + tt1] * wp[c * 168];
        float sc = g1[o] / sqrtf(v1[o] + EPSB);
        s = (s - m1[o]) * sc + bb1[o];
        s = (s >= 0.f) ? s : a1 * s;
        bufA[o * 65 + tt2] = s;
    }
    __syncthreads();

    for (int i = tid; i < 42 * 8 * nt0; i += 512) {
        int o = i % 42, tt3 = i / 42;
        int tt2 = tt3 >> 1, k = tt3 & 1;
        const float* wp = W2 + o * 2 + k;
        float s = 0.f;
        for (int c = 0; c < 84; ++c) s += bufA[c * 65 + tt2] * wp[c * 84];
        float sc = g2[o] / sqrtf(v2[o] + EPSB);
        s = (s - m2[o]) * sc + bb2[o];
        s = (s >= 0.f) ? s : a2 * s;
        int t3 = 8 * ta + tt3;
        hseq[(size_t)t3 * (BATCH * 42) + b * 42 + o] = s;
    }
}

// ================= table: gi-contribution of one-hot px =====================
__global__ void table_kernel(const float* __restrict__ w_px, const float* __restrict__ b_px,
                             const float* __restrict__ w_ih, const float* __restrict__ b_ih,
                             float* __restrict__ table)
{
    int i = blockIdx.x * 256 + threadIdx.x;
    if (i >= 22 * 1536) return;
    int e = i / 1536, jg = i % 1536;
    const float* wih = w_ih + jg * 63 + 42;
    float s = b_ih[jg];
    #pragma unroll
    for (int jp = 0; jp < NC; ++jp) {
        float px = b_px[jp] + (e < NC ? w_px[jp * NC + e] : 0.f);
        s += px * wih[jp];
    }
    table[i] = s;
}

// ====== pack weights into MFMA B-fragment order, fp16 2-limb (lo x2048) =====
// whh: [g][nf(32)][kf(16)][lane(64)*8]; lane l supplies B[k=(l>>4)*8+e][n=l&15]
__global__ void pack_whh_kernel(const float* __restrict__ w_hh,
                                _Float16* __restrict__ pH, _Float16* __restrict__ pL)
{
    int i = blockIdx.x * 256 + threadIdx.x;
    if (i >= 3 * 32 * 16 * 512) return;
    int e = i & 7, l = (i >> 3) & 63, kf = (i >> 9) & 15, nf = (i >> 13) & 31, g = i >> 18;
    int n = nf * 16 + (l & 15);
    int k = kf * 32 + ((l >> 4) << 3) + e;
    float v = w_hh[(size_t)(g * GHID + n) * GHID + k];
    _Float16 hi, lo; split2(v, hi, lo);
    pH[i] = hi; pL[i] = lo;
}

__global__ void pack_wih_kernel(const float* __restrict__ w_ih,
                                _Float16* __restrict__ pH, _Float16* __restrict__ pL)
{
    int i = blockIdx.x * 256 + threadIdx.x;
    if (i >= 3 * 32 * 2 * 512) return;
    int e = i & 7, l = (i >> 3) & 63, kf = (i >> 9) & 1, nf = (i >> 10) & 31, g = i >> 15;
    int n = nf * 16 + (l & 15);
    int k = kf * 32 + ((l >> 4) << 3) + e;
    float v = (k < 42) ? w_ih[(size_t)(g * GHID + n) * 63 + k] : 0.f;
    _Float16 hi, lo; split2(v, hi, lo);
    pH[i] = hi; pL[i] = lo;
}

__global__ void pack_wout_kernel(const float* __restrict__ w_out,
                                 _Float16* __restrict__ pH, _Float16* __restrict__ pL)
{
    int i = blockIdx.x * 256 + threadIdx.x;
    if (i >= 2 * 16 * 512) return;
    int e = i & 7, l = (i >> 3) & 63, kf = (i >> 9) & 15, nf = i >> 13;
    int n = nf * 16 + (l & 15);
    int k = kf * 32 + ((l >> 4) << 3) + e;
    float v = (n < NC) ? w_out[(size_t)n * GHID + k] : 0.f;
    _Float16 hi, lo; split2(v, hi, lo);
    pH[i] = hi; pL[i] = lo;
}

// ============== persistent zero-communication decode, 32 rows/block =========
// 64 blocks x 512 thr (8 waves); block owns 32 batch rows for ALL 500 steps.
// h in LDS (2-limb fp16 planes, XOR-swizzled elem^=(row&7)<<3), in-place
// update via register staging. 8 blocks/XCD all read the SAME 3.8 MB packed
// weight set -> L2-resident. Logits once/row (waves 0-3) || hseq staging
// (waves 4-7). No cross-block state, no atomics, no grid sync.
#define MFMA3(mainA, crossA, aH_, aL_, bH_, bL_) do {                              \
    mainA  = __builtin_amdgcn_mfma_f32_16x16x32_f16(aH_, bH_, mainA, 0, 0, 0);     \
    crossA = __builtin_amdgcn_mfma_f32_16x16x32_f16(aH_, bL_, crossA, 0, 0, 0);    \
    crossA = __builtin_amdgcn_mfma_f32_16x16x32_f16(aL_, bH_, crossA, 0, 0, 0);    \
} while (0)

__global__ __launch_bounds__(512, 2) void gru_rows32(
    const float* __restrict__ hseq,
    const float* __restrict__ table,
    const _Float16* __restrict__ whhH, const _Float16* __restrict__ whhL,
    const _Float16* __restrict__ wihH, const _Float16* __restrict__ wihL,
    const _Float16* __restrict__ woH,  const _Float16* __restrict__ woL,
    const float* __restrict__ b_hh, const float* __restrict__ b_out,
    float* __restrict__ out)
{
    __shared__ _Float16 hH[ROWS * 512];      // 32 KB, swizzled
    __shared__ _Float16 hL[ROWS * 512];      // 32 KB
    __shared__ _Float16 tH[2][ROWS * 64];    // 8 KB, hseq tiles, swizzled
    __shared__ _Float16 tL[2][ROWS * 64];    // 8 KB
    __shared__ float    lg[ROWS][33];
    __shared__ int      idx_l[ROWS];

    const int tid  = threadIdx.x;
    const int l    = tid & 63, wv = tid >> 6;
    const int lrow = l & 15, lk = (l >> 4) << 3;
    const int row0 = blockIdx.x * ROWS;
    const int nfb  = wv * 4;                 // this wave's 4 nf (gates)

    // ---- prologue: zero h, zero hseq tiles, stage hseq[0], idx = NC --------
    for (int i = tid; i < ROWS * 512; i += 512) { hH[i] = (_Float16)0.f; hL[i] = (_Float16)0.f; }
    for (int i = tid; i < ROWS * 64; i += 512) {
        tH[0][i] = (_Float16)0.f; tH[1][i] = (_Float16)0.f;
        tL[0][i] = (_Float16)0.f; tL[1][i] = (_Float16)0.f;
    }
    if (tid < ROWS) idx_l[tid] = NC;
    __syncthreads();
    for (int i = tid; i < ROWS * 42; i += 512) {
        int r = i / 42, k = i % 42;
        float f = hseq[(size_t)(row0 + r) * 42 + k];
        _Float16 hi, lo; split2(f, hi, lo);
        int o = r * 64 + (k ^ ((r & 7) << 3));
        tH[0][o] = hi; tL[0][o] = lo;
    }
    __syncthreads();

    for (int t = 0; t < REAL_NL; ++t) {
        const int pp = t & 1, pn = pp ^ 1;

        // ------------------ gates: K-loop over h (LDS) -----------------------
        // streams: 0=r, 1=z, 2=in(I), 3=hn(H); acc[stream][j][mi]
        f32x4 gM[4][4][2], gX[4][4][2];
        #pragma unroll
        for (int s = 0; s < 4; ++s)
            #pragma unroll
            for (int j = 0; j < 4; ++j)
                #pragma unroll
                for (int mi = 0; mi < 2; ++mi) {
                    gM[s][j][mi] = (f32x4)0.f; gX[s][j][mi] = (f32x4)0.f;
                }

        for (int kf = 0; kf < 16; ++kf) {
            half8 aH[2], aL[2];
            #pragma unroll
            for (int mi = 0; mi < 2; ++mi) {
                int ao = (mi * 16 + lrow) * 512 + ((kf * 32 + lk) ^ ((lrow & 7) << 3));
                aH[mi] = *(const half8*)(&hH[ao]);
                aL[mi] = *(const half8*)(&hL[ao]);
            }
            #pragma unroll
            for (int g = 0; g < 3; ++g) {
                #pragma unroll
                for (int j = 0; j < 4; ++j) {
                    size_t bo = ((size_t)((g * 32 + nfb + j) * 16 + kf) << 9) + (l << 3);
                    half8 bH = *(const half8*)(whhH + bo);
                    half8 bL = *(const half8*)(whhL + bo);
                    const int s = (g == 2) ? 3 : g;
                    #pragma unroll
                    for (int mi = 0; mi < 2; ++mi) {
                        MFMA3(gM[s][j][mi], gX[s][j][mi], aH[mi], aL[mi], bH, bL);
                    }
                }
            }
        }
        // I part: K = 64 (42 real) from staged hseq tile
        #pragma unroll
        for (int kf = 0; kf < 2; ++kf) {
            half8 aH[2], aL[2];
            #pragma unroll
            for (int mi = 0; mi < 2; ++mi) {
                int ao = (mi * 16 + lrow) * 64 + ((kf * 32 + lk) ^ ((lrow & 7) << 3));
                aH[mi] = *(const half8*)(&tH[pp][ao]);
                aL[mi] = *(const half8*)(&tL[pp][ao]);
            }
            #pragma unroll
            for (int g = 0; g < 3; ++g) {
                #pragma unroll
                for (int j = 0; j < 4; ++j) {
                    size_t bo = ((size_t)((g * 32 + nfb + j) * 2 + kf) << 9) + (l << 3);
                    half8 bH = *(const half8*)(wihH + bo);
                    half8 bL = *(const half8*)(wihL + bo);
                    const int s = (g == 2) ? 2 : g;
                    #pragma unroll
                    for (int mi = 0; mi < 2; ++mi) {
                        MFMA3(gM[s][j][mi], gX[s][j][mi], aH[mi], aL[mi], bH, bL);
                    }
                }
            }
        }

        // ---- epilogue: gate math into registers (reads h LDS pre-sync) ------
        float hnv[4][2][4];
        #pragma unroll
        for (int j = 0; j < 4; ++j) {
            int c = (nfb + j) * 16 + lrow;
            float bhr = b_hh[c], bhz = b_hh[GHID + c], bhn = b_hh[2 * GHID + c];
            #pragma unroll
            for (int mi = 0; mi < 2; ++mi) {
                #pragma unroll
                for (int r = 0; r < 4; ++r) {
                    int rl = mi * 16 + ((l >> 4) << 2) + r;   // local row 0..31
                    const float* tb = table + idx_l[rl] * 1536;
                    float rv  = gM[0][j][mi][r] + gX[0][j][mi][r] * INV_LO + bhr + tb[c];
                    float zv  = gM[1][j][mi][r] + gX[1][j][mi][r] * INV_LO + bhz + tb[GHID + c];
                    float inp = gM[2][j][mi][r] + gX[2][j][mi][r] * INV_LO + tb[2 * GHID + c];
                    float hnp = gM[3][j][mi][r] + gX[3][j][mi][r] * INV_LO + bhn;
                    float rg = 1.f / (1.f + expf(-rv));
                    float zg = 1.f / (1.f + expf(-zv));
                    float ng = tanhf(inp + rg * hnp);
                    int ho = rl * 512 + (c ^ ((rl & 7) << 3));
                    float hpv = (float)hH[ho] + (float)hL[ho] * INV_LO;
                    hnv[j][mi][r] = (1.f - zg) * ng + zg * hpv;
                }
            }
        }
        __syncthreads();     // all reads of h[t] complete

        // ---- write h[t+1] in place ------------------------------------------
        #pragma unroll
        for (int j = 0; j < 4; ++j) {
            int c = (nfb + j) * 16 + lrow;
            #pragma unroll
            for (int mi = 0; mi < 2; ++mi) {
                #pragma unroll
                for (int r = 0; r < 4; ++r) {
                    int rl = mi * 16 + ((l >> 4) << 2) + r;
                    int ho = rl * 512 + (c ^ ((rl & 7) << 3));
                    _Float16 hi, lo; split2(hnv[j][mi][r], hi, lo);
                    hH[ho] = hi; hL[ho] = lo;
                }
            }
        }
        __syncthreads();     // h[t+1] visible

        // ---- logits once/row (waves 0-3) || stage hseq[t+1] (waves 4-7) -----
        if (wv < 4) {
            const int lnf = wv & 1, mi = wv >> 1;
            f32x4 lM = (f32x4)0.f, lX = (f32x4)0.f;
            for (int kf = 0; kf < 16; ++kf) {
                int ao = (mi * 16 + lrow) * 512 + ((kf * 32 + lk) ^ ((lrow & 7) << 3));
                half8 aH = *(const half8*)(&hH[ao]);
                half8 aL = *(const half8*)(&hL[ao]);
                size_t bo = ((size_t)(lnf * 16 + kf) << 9) + (l << 3);
                half8 bH = *(const half8*)(woH + bo);
                half8 bL = *(const half8*)(woL + bo);
                MFMA3(lM, lX, aH, aL, bH, bL);
            }
            int col = lnf * 16 + lrow;
            float bias = (col < NC) ? b_out[col] : 0.f;
            #pragma unroll
            for (int r = 0; r < 4; ++r)
                lg[mi * 16 + ((l >> 4) << 2) + r][col] = lM[r] + lX[r] * INV_LO + bias;
        } else {
            int s0 = tid - 256;
            for (int i = s0; i < ROWS * 42; i += 256) {
                int r = i / 42, k = i % 42;
                float f = hseq[(size_t)(t + 1) * (BATCH * 42) + (size_t)(row0 + r) * 42 + k];
                _Float16 hi, lo; split2(f, hi, lo);
                int o = r * 64 + (k ^ ((r & 7) << 3));
                tH[pn][o] = hi; tL[pn][o] = lo;
            }
        }
        __syncthreads();

        // ---- argmax (first-max) + out[t] ------------------------------------
        if (tid < ROWS) {
            float best = lg[tid][0]; int bi = 0;
            #pragma unroll
            for (int c = 1; c < NC; ++c) {
                float v = lg[tid][c];
                if (v > best) { best = v; bi = c; }   // strict > keeps first max
            }
            idx_l[tid] = bi;
            float* op = out + (size_t)(row0 + tid) * (REAL_NL * NC) + (size_t)t * NC;
            #pragma unroll
            for (int c = 0; c < NC; ++c) op[c] = lg[tid][c];
        }
        __syncthreads();
    }
}

// ============================================================================
extern "C" void kernel_launch(void* const* d_in, const int* in_sizes, int n_in,
                              void* d_out, int out_size, void* d_ws, size_t ws_size,
                              hipStream_t stream)
{
    const float* z    = (const float*)d_in[1];
    const float* dW   = (const float*)d_in[3];
    const float* db   = (const float*)d_in[4];
    const float* W0   = (const float*)d_in[5];
    const float* g0   = (const float*)d_in[6];
    const float* bb0  = (const float*)d_in[7];
    const float* m0   = (const float*)d_in[8];
    const float* v0   = (const float*)d_in[9];
    const float* al0  = (const float*)d_in[10];
    const float* W1   = (const float*)d_in[11];
    const float* g1   = (const float*)d_in[12];
    const float* bb1  = (const float*)d_in[13];
    const float* m1   = (const float*)d_in[14];
    const float* v1   = (const float*)d_in[15];
    const float* al1  = (const float*)d_in[16];
    const float* W2   = (const float*)d_in[17];
    const float* g2   = (const float*)d_in[18];
    const float* bb2  = (const float*)d_in[19];
    const float* m2   = (const float*)d_in[20];
    const float* v2   = (const float*)d_in[21];
    const float* al2  = (const float*)d_in[22];
    const float* w_px = (const float*)d_in[23];
    const float* b_px = (const float*)d_in[24];
    const float* w_ih = (const float*)d_in[25];
    const float* w_hh = (const float*)d_in[26];
    const float* b_ih = (const float*)d_in[27];
    const float* b_hh = (const float*)d_in[28];
    const float* w_out= (const float*)d_in[29];
    const float* b_out= (const float*)d_in[30];
    float* out = (float*)d_out;

    // ws: hseq(f32) | whh H/L | wih H/L | wo H/L | table
    float* ws = (float*)d_ws;
    float* hseq = ws;                                            // 504*2048*42 f32
    _Float16* whhH = (_Float16*)(hseq + (size_t)NLFULL * BATCH * 42);
    _Float16* whhL = whhH + 3 * 32 * 16 * 512;
    _Float16* wihH = whhL + 3 * 32 * 16 * 512;
    _Float16* wihL = wihH + 3 * 32 * 2 * 512;
    _Float16* woH  = wihL + 3 * 32 * 2 * 512;
    _Float16* woL  = woH + 2 * 16 * 512;
    float* table = (float*)(woL + 2 * 16 * 512);                 // 22*1536

    upsample_kernel<<<dim3(BATCH, 4), 512, 0, stream>>>(
        z, dW, db,
        W0, g0, bb0, m0, v0, al0,
        W1, g1, bb1, m1, v1, al1,
        W2, g2, bb2, m2, v2, al2,
        hseq);

    table_kernel<<<(22 * 1536 + 255) / 256, 256, 0, stream>>>(w_px, b_px, w_ih, b_ih, table);
    pack_whh_kernel<<<(3 * 32 * 16 * 512 + 255) / 256, 256, 0, stream>>>(w_hh, whhH, whhL);
    pack_wih_kernel<<<(3 * 32 * 2 * 512 + 255) / 256, 256, 0, stream>>>(w_ih, wihH, wihL);
    pack_wout_kernel<<<(2 * 16 * 512 + 255) / 256, 256, 0, stream>>>(w_out, woH, woL);

    gru_rows32<<<64, 512, 0, stream>>>(
        hseq, table, whhH, whhL, wihH, wihL, woH, woL, b_hh, b_out, out);
}

// Round 12
// 53016.022 us; speedup vs baseline: 1.5603x; 1.5603x over previous
//
#include <hip/hip_runtime.h>
#include <math.h>

#define NLFULL 504
#define REAL_NL 500
#define BATCH 2048
#define NZ 50
#define NC 21
#define GHID 512
#define EPSB 1e-5f
#define LO_SCALE 2048.0f
#define INV_LO (1.0f / 2048.0f)

typedef __attribute__((ext_vector_type(4))) float f32x4;
typedef __attribute__((ext_vector_type(8))) _Float16 half8;

__device__ __forceinline__ void split2(float x, _Float16& hi, _Float16& lo) {
    hi = (_Float16)x;
    lo = (_Float16)((x - (float)hi) * LO_SCALE);
}
__device__ __forceinline__ unsigned packh(float x) {
    _Float16 hi, lo; split2(x, hi, lo);
    return (unsigned)__builtin_bit_cast(unsigned short, hi)
         | ((unsigned)__builtin_bit_cast(unsigned short, lo) << 16);
}

// =============================== upsample ==================================
__global__ __launch_bounds__(512) void upsample_kernel(
    const float* __restrict__ z, const float* __restrict__ dW, const float* __restrict__ db,
    const float* __restrict__ W0, const float* __restrict__ g0, const float* __restrict__ bb0,
    const float* __restrict__ m0, const float* __restrict__ v0, const float* __restrict__ al0,
    const float* __restrict__ W1, const float* __restrict__ g1, const float* __restrict__ bb1,
    const float* __restrict__ m1, const float* __restrict__ v1, const float* __restrict__ al1,
    const float* __restrict__ W2, const float* __restrict__ g2, const float* __restrict__ bb2,
    const float* __restrict__ m2, const float* __restrict__ v2, const float* __restrict__ al2,
    float* __restrict__ hseq)
{
    __shared__ float bufA[5712];
    __shared__ float bufB[5544];
    __shared__ float zl[52];

    const int b   = blockIdx.x;
    const int ta  = blockIdx.y * 16;
    const int nt0 = min(16, 63 - ta);
    const int tid = threadIdx.x;

    if (tid < NZ) zl[tid] = z[b * NZ + tid];
    __syncthreads();

    for (int i = tid; i < 336 * nt0; i += 512) {
        int c = i % 336, tt = i / 336;
        int row = c * 63 + ta + tt;
        const float* wr = dW + (size_t)row * NZ;
        float s = db[row];
        #pragma unroll
        for (int n = 0; n < NZ; ++n) s += zl[n] * wr[n];
        bufA[c * 17 + tt] = s;
    }
    __syncthreads();

    const float a0 = al0[0], a1 = al1[0], a2 = al2[0];

    for (int i = tid; i < 168 * 2 * nt0; i += 512) {
        int o = i % 168, tt1 = i / 168;
        int tt = tt1 >> 1, k = tt1 & 1;
        const float* wp = W0 + o * 2 + k;
        float s = 0.f;
        for (int c = 0; c < 336; ++c) s += bufA[c * 17 + tt] * wp[c * 336];
        float sc = g0[o] / sqrtf(v0[o] + EPSB);
        s = (s - m0[o]) * sc + bb0[o];
        s = (s >= 0.f) ? s : a0 * s;
        bufB[o * 33 + tt1] = s;
    }
    __syncthreads();

    for (int i = tid; i < 84 * 4 * nt0; i += 512) {
        int o = i % 84, tt2 = i / 84;
        int tt1 = tt2 >> 1, k = tt2 & 1;
        const float* wp = W1 + o * 2 + k;
        float s = 0.f;
        for (int c = 0; c < 168; ++c) s += bufB[c * 33 + tt1] * wp[c * 168];
        float sc = g1[o] / sqrtf(v1[o] + EPSB);
        s = (s - m1[o]) * sc + bb1[o];
        s = (s >= 0.f) ? s : a1 * s;
        bufA[o * 65 + tt2] = s;
    }
    __syncthreads();

    for (int i = tid; i < 42 * 8 * nt0; i += 512) {
        int o = i % 42, tt3 = i / 42;
        int tt2 = tt3 >> 1, k = tt3 & 1;
        const float* wp = W2 + o * 2 + k;
        float s = 0.f;
        for (int c = 0; c < 84; ++c) s += bufA[c * 65 + tt2] * wp[c * 84];
        float sc = g2[o] / sqrtf(v2[o] + EPSB);
        s = (s - m2[o]) * sc + bb2[o];
        s = (s >= 0.f) ? s : a2 * s;
        int t3 = 8 * ta + tt3;
        hseq[(size_t)t3 * (BATCH * 42) + b * 42 + o] = s;
    }
}

// ================= table: gi-contribution of one-hot px =====================
__global__ void table_kernel(const float* __restrict__ w_px, const float* __restrict__ b_px,
                             const float* __restrict__ w_ih, const float* __restrict__ b_ih,
                             float* __restrict__ table)
{
    int i = blockIdx.x * 256 + threadIdx.x;
    if (i >= 22 * 1536) return;
    int e = i / 1536, jg = i % 1536;
    const float* wih = w_ih + jg * 63 + 42;
    float s = b_ih[jg];
    #pragma unroll
    for (int jp = 0; jp < NC; ++jp) {
        float px = b_px[jp] + (e < NC ? w_px[jp * NC + e] : 0.f);
        s += px * wih[jp];
    }
    table[i] = s;
}

// ====== pack weights into MFMA B-fragment order, fp16 2-limb (lo x2048) =====
__global__ void pack_whh_kernel(const float* __restrict__ w_hh,
                                _Float16* __restrict__ pH, _Float16* __restrict__ pL)
{
    int i = blockIdx.x * 256 + threadIdx.x;
    if (i >= 3 * 32 * 16 * 512) return;
    int e = i & 7, l = (i >> 3) & 63, kf = (i >> 9) & 15, nf = (i >> 13) & 31, g = i >> 18;
    int n = nf * 16 + (l & 15);
    int k = kf * 32 + ((l >> 4) << 3) + e;
    float v = w_hh[(size_t)(g * GHID + n) * GHID + k];
    _Float16 hi, lo; split2(v, hi, lo);
    pH[i] = hi; pL[i] = lo;
}

__global__ void pack_wih_kernel(const float* __restrict__ w_ih,
                                _Float16* __restrict__ pH, _Float16* __restrict__ pL)
{
    int i = blockIdx.x * 256 + threadIdx.x;
    if (i >= 3 * 32 * 2 * 512) return;
    int e = i & 7, l = (i >> 3) & 63, kf = (i >> 9) & 1, nf = (i >> 10) & 31, g = i >> 15;
    int n = nf * 16 + (l & 15);
    int k = kf * 32 + ((l >> 4) << 3) + e;
    float v = (k < 42) ? w_ih[(size_t)(g * GHID + n) * 63 + k] : 0.f;
    _Float16 hi, lo; split2(v, hi, lo);
    pH[i] = hi; pL[i] = lo;
}

__global__ void pack_wout_kernel(const float* __restrict__ w_out,
                                 _Float16* __restrict__ pH, _Float16* __restrict__ pL)
{
    int i = blockIdx.x * 256 + threadIdx.x;
    if (i >= 2 * 16 * 512) return;
    int e = i & 7, l = (i >> 3) & 63, kf = (i >> 9) & 15, nf = i >> 13;
    int n = nf * 16 + (l & 15);
    int k = kf * 32 + ((l >> 4) << 3) + e;
    float v = (n < NC) ? w_out[(size_t)n * GHID + k] : 0.f;
    _Float16 hi, lo; split2(v, hi, lo);
    pH[i] = hi; pL[i] = lo;
}

// =========================== init barrier ===================================
__global__ void init_kernel(int* __restrict__ bar)
{
    if (blockIdx.x == 0 && threadIdx.x < 64) bar[threadIdx.x] = 0;
}

// ================ persistent column-split decode ============================
// 256 blocks x 512 thr, 1/CU (LDS 137 KB), cooperative. bid&7 = col-slice =
// XCD -> per-XCD weight slice ~0.7 MB L2-RESIDENT. bid>>3 = row-group (64
// rows). Full-width h[64][512] in LDS (2-limb fp16, XOR-swizzled). Per step:
// gates (LDS-A x L2-B) -> coalesced agent-atomic u32 stores of h_new ->
// global barrier -> copy phase (8B agent-atomic loads -> LDS, the ONLY
// uncached reads) -> logits from LDS (per-block, no idx exchange) -> argmax.
#define MFMA3(mainA, crossA, aH_, aL_, bH_, bL_) do {                              \
    mainA  = __builtin_amdgcn_mfma_f32_16x16x32_f16(aH_, bH_, mainA, 0, 0, 0);     \
    crossA = __builtin_amdgcn_mfma_f32_16x16x32_f16(aH_, bL_, crossA, 0, 0, 0);    \
    crossA = __builtin_amdgcn_mfma_f32_16x16x32_f16(aL_, bH_, crossA, 0, 0, 0);    \
} while (0)

struct GruP {
    const float* hseq;
    const float* table;
    const _Float16 *whhH, *whhL, *wihH, *wihL, *woH, *woL;
    const float *b_hh, *b_out;
    float* out;
    unsigned *gbufA, *gbufB;
    int* bar;
};

__global__ __launch_bounds__(512, 2) void gru_persist(GruP p)
{
    __shared__ _Float16 hH[64 * 512];     // 64 KB, swizzled elem^=(row&7)<<3
    __shared__ _Float16 hL[64 * 512];     // 64 KB
    __shared__ float    lg[64][33];       // 8.4 KB
    __shared__ int      idx_l[64];

    const int bid = blockIdx.x;
    const int cb  = bid & 7;              // col-slice == XCD heuristic
    const int rb  = bid >> 3;             // row-group 0..31
    const int row0 = rb * 64;
    const int tid = threadIdx.x;
    const int l   = tid & 63, wv = tid >> 6;
    const int lrow = l & 15, lk = (l >> 4) << 3;

    const int mi2 = wv >> 2;              // 0..1 : two 16-row A-frags each
    const int nfl = wv & 3;               // 0..3 : local n-frag
    const int nfg = cb * 4 + nfl;         // global n-frag 0..31
    const int c   = nfg * 16 + lrow;      // this lane's output column

    // ---- prologue: h[-1] = 0, idx = NC -------------------------------------
    for (int i = tid; i < 64 * 512; i += 512) { hH[i] = (_Float16)0.f; hL[i] = (_Float16)0.f; }
    if (tid < 64) idx_l[tid] = NC;
    __syncthreads();

    const float bhr = p.b_hh[c], bhz = p.b_hh[GHID + c], bhn = p.b_hh[2 * GHID + c];

    for (int t = 0; t < REAL_NL; ++t) {
        unsigned* gbuf = (t & 1) ? p.gbufB : p.gbufA;
        const float* ht = p.hseq + (size_t)t * (BATCH * 42);

        // ---------------- gates: h[t] from LDS h[t-1] ------------------------
        {
            // streams: 0=r 1=z 2=in(I) 3=hn(H); [stream][mi]
            f32x4 gM[4][2], gX[4][2];
            #pragma unroll
            for (int s = 0; s < 4; ++s) {
                #pragma unroll
                for (int mi = 0; mi < 2; ++mi) { gM[s][mi] = (f32x4)0.f; gX[s][mi] = (f32x4)0.f; }
            }

            for (int kf = 0; kf < 16; ++kf) {
                half8 aH[2], aL[2];
                #pragma unroll
                for (int mi = 0; mi < 2; ++mi) {
                    int lm = (mi2 * 2 + mi) * 16 + lrow;
                    int ao = lm * 512 + ((kf * 32 + lk) ^ ((lm & 7) << 3));
                    aH[mi] = *(const half8*)(&hH[ao]);
                    aL[mi] = *(const half8*)(&hL[ao]);
                }
                #pragma unroll
                for (int g = 0; g < 3; ++g) {
                    size_t bo = ((size_t)((g * 32 + nfg) * 16 + kf) << 9) + (l << 3);
                    half8 bH = *(const half8*)(p.whhH + bo);
                    half8 bL = *(const half8*)(p.whhL + bo);
                    const int s = (g == 2) ? 3 : g;
                    #pragma unroll
                    for (int mi = 0; mi < 2; ++mi) {
                        MFMA3(gM[s][mi], gX[s][mi], aH[mi], aL[mi], bH, bL);
                    }
                }
            }
            // I part: K = 42 (plain cached loads, on-the-fly split)
            #pragma unroll
            for (int kf = 0; kf < 2; ++kf) {
                half8 aH[2], aL[2];
                #pragma unroll
                for (int mi = 0; mi < 2; ++mi) {
                    const float* rp = ht + (size_t)(row0 + (mi2 * 2 + mi) * 16 + lrow) * 42;
                    #pragma unroll
                    for (int e = 0; e < 8; ++e) {
                        int k = kf * 32 + lk + e;
                        float f = (k < 42) ? rp[k] : 0.f;
                        _Float16 hi, lo; split2(f, hi, lo);
                        aH[mi][e] = hi; aL[mi][e] = lo;
                    }
                }
                #pragma unroll
                for (int g = 0; g < 3; ++g) {
                    size_t bo = ((size_t)((g * 32 + nfg) * 2 + kf) << 9) + (l << 3);
                    half8 bH = *(const half8*)(p.wihH + bo);
                    half8 bL = *(const half8*)(p.wihL + bo);
                    const int s = (g == 2) ? 2 : g;
                    #pragma unroll
                    for (int mi = 0; mi < 2; ++mi) {
                        MFMA3(gM[s][mi], gX[s][mi], aH[mi], aL[mi], bH, bL);
                    }
                }
            }

            // epilogue: D row=(l>>4)*4+r, col=l&15; coalesced atomic u32 stores
            #pragma unroll
            for (int mi = 0; mi < 2; ++mi) {
                #pragma unroll
                for (int r = 0; r < 4; ++r) {
                    int lm = (mi2 * 2 + mi) * 16 + ((l >> 4) << 2) + r;
                    const float* tb = p.table + idx_l[lm] * 1536;
                    float rv  = gM[0][mi][r] + gX[0][mi][r] * INV_LO + bhr + tb[c];
                    float zv  = gM[1][mi][r] + gX[1][mi][r] * INV_LO + bhz + tb[GHID + c];
                    float inp = gM[2][mi][r] + gX[2][mi][r] * INV_LO + tb[2 * GHID + c];
                    float hnp = gM[3][mi][r] + gX[3][mi][r] * INV_LO + bhn;
                    float rg = 1.f / (1.f + expf(-rv));
                    float zg = 1.f / (1.f + expf(-zv));
                    float ng = tanhf(inp + rg * hnp);
                    int ho = lm * 512 + (c ^ ((lm & 7) << 3));
                    float hpv = (float)hH[ho] + (float)hL[ho] * INV_LO;
                    float hnv = (1.f - zg) * ng + zg * hpv;
                    __hip_atomic_store(gbuf + (size_t)(row0 + lm) * 512 + c, packh(hnv),
                                       __ATOMIC_RELAXED, __HIP_MEMORY_SCOPE_AGENT);
                }
            }
        }

        // ---------------- global barrier ------------------------------------
        __syncthreads();
        if (tid == 0) {
            __hip_atomic_fetch_add(p.bar, 1, __ATOMIC_RELEASE, __HIP_MEMORY_SCOPE_AGENT);
            int target = (t + 1) * 256;
            while (__hip_atomic_load(p.bar, __ATOMIC_ACQUIRE, __HIP_MEMORY_SCOPE_AGENT) < target)
                __builtin_amdgcn_s_sleep(2);
        }
        __syncthreads();

        // ---------------- copy phase: gbuf -> LDS (coherent loads) -----------
        {
            const unsigned long long* src =
                (const unsigned long long*)(gbuf + (size_t)row0 * 512);
            for (int i = tid; i < 64 * 256; i += 512) {     // 32 iters of 8B
                unsigned long long d = __hip_atomic_load(
                    (unsigned long long*)(src + i), __ATOMIC_RELAXED, __HIP_MEMORY_SCOPE_AGENT);
                int e = i * 2;
                int r = e >> 9, cc = e & 511;               // cc even
                unsigned w0 = (unsigned)d, w1 = (unsigned)(d >> 32);
                int o = r * 512 + (cc ^ ((r & 7) << 3));
                *(unsigned*)&hH[o] = (w0 & 0xFFFFu) | (w1 << 16);
                *(unsigned*)&hL[o] = (w0 >> 16) | (w1 & 0xFFFF0000u);
            }
        }
        __syncthreads();

        // ---------------- logits from LDS h[t] -------------------------------
        {
            const int lmi = wv >> 1, wnf = wv & 1;
            f32x4 lM = (f32x4)0.f, lX = (f32x4)0.f;
            for (int kf = 0; kf < 16; ++kf) {
                int lm = lmi * 16 + lrow;
                int ao = lm * 512 + ((kf * 32 + lk) ^ ((lm & 7) << 3));
                half8 aH = *(const half8*)(&hH[ao]);
                half8 aL = *(const half8*)(&hL[ao]);
                size_t bo = ((size_t)(wnf * 16 + kf) << 9) + (l << 3);
                half8 bH = *(const half8*)(p.woH + bo);
                half8 bL = *(const half8*)(p.woL + bo);
                MFMA3(lM, lX, aH, aL, bH, bL);
            }
            int col = wnf * 16 + lrow;
            float bias = (col < NC) ? p.b_out[col] : 0.f;
            #pragma unroll
            for (int r = 0; r < 4; ++r)
                lg[lmi * 16 + ((l >> 4) << 2) + r][col] = lM[r] + lX[r] * INV_LO + bias;
        }
        __syncthreads();

        // ---------------- argmax (first-max) + out[t] -------------------------
        if (tid < 64) {
            float best = lg[tid][0]; int bi = 0;
            #pragma unroll
            for (int cc2 = 1; cc2 < NC; ++cc2) {
                float v = lg[tid][cc2];
                if (v > best) { best = v; bi = cc2; }   // strict > keeps first max
            }
            idx_l[tid] = bi;
            if (cb == 0) {
                float* op = p.out + (size_t)(row0 + tid) * (REAL_NL * NC) + (size_t)t * NC;
                #pragma unroll
                for (int cc2 = 0; cc2 < NC; ++cc2) op[cc2] = lg[tid][cc2];
            }
        }
        __syncthreads();
    }
}

// ============================================================================
extern "C" void kernel_launch(void* const* d_in, const int* in_sizes, int n_in,
                              void* d_out, int out_size, void* d_ws, size_t ws_size,
                              hipStream_t stream)
{
    const float* z    = (const float*)d_in[1];
    const float* dW   = (const float*)d_in[3];
    const float* db   = (const float*)d_in[4];
    const float* W0   = (const float*)d_in[5];
    const float* g0   = (const float*)d_in[6];
    const float* bb0  = (const float*)d_in[7];
    const float* m0   = (const float*)d_in[8];
    const float* v0   = (const float*)d_in[9];
    const float* al0  = (const float*)d_in[10];
    const float* W1   = (const float*)d_in[11];
    const float* g1   = (const float*)d_in[12];
    const float* bb1  = (const float*)d_in[13];
    const float* m1   = (const float*)d_in[14];
    const float* v1   = (const float*)d_in[15];
    const float* al1  = (const float*)d_in[16];
    const float* W2   = (const float*)d_in[17];
    const float* g2   = (const float*)d_in[18];
    const float* bb2  = (const float*)d_in[19];
    const float* m2   = (const float*)d_in[20];
    const float* v2   = (const float*)d_in[21];
    const float* al2  = (const float*)d_in[22];
    const float* w_px = (const float*)d_in[23];
    const float* b_px = (const float*)d_in[24];
    const float* w_ih = (const float*)d_in[25];
    const float* w_hh = (const float*)d_in[26];
    const float* b_ih = (const float*)d_in[27];
    const float* b_hh = (const float*)d_in[28];
    const float* w_out= (const float*)d_in[29];
    const float* b_out= (const float*)d_in[30];
    float* out = (float*)d_out;

    // ws: hseq(f32) | whh H/L | wih H/L | wo H/L | table | gbufA | gbufB | bar
    float* ws = (float*)d_ws;
    float* hseq = ws;                                            // 504*2048*42 f32
    _Float16* whhH = (_Float16*)(hseq + (size_t)NLFULL * BATCH * 42);
    _Float16* whhL = whhH + 3 * 32 * 16 * 512;
    _Float16* wihH = whhL + 3 * 32 * 16 * 512;
    _Float16* wihL = wihH + 3 * 32 * 2 * 512;
    _Float16* woH  = wihL + 3 * 32 * 2 * 512;
    _Float16* woL  = woH + 2 * 16 * 512;
    float* table   = (float*)(woL + 2 * 16 * 512);               // 22*1536
    unsigned* gbufA = (unsigned*)(table + 22 * 1536);            // 2048*512 u32
    unsigned* gbufB = gbufA + (size_t)BATCH * GHID;
    int* bar       = (int*)(gbufB + (size_t)BATCH * GHID);       // 64

    upsample_kernel<<<dim3(BATCH, 4), 512, 0, stream>>>(
        z, dW, db,
        W0, g0, bb0, m0, v0, al0,
        W1, g1, bb1, m1, v1, al1,
        W2, g2, bb2, m2, v2, al2,
        hseq);

    table_kernel<<<(22 * 1536 + 255) / 256, 256, 0, stream>>>(w_px, b_px, w_ih, b_ih, table);
    pack_whh_kernel<<<(3 * 32 * 16 * 512 + 255) / 256, 256, 0, stream>>>(w_hh, whhH, whhL);
    pack_wih_kernel<<<(3 * 32 * 2 * 512 + 255) / 256, 256, 0, stream>>>(w_ih, wihH, wihL);
    pack_wout_kernel<<<(2 * 16 * 512 + 255) / 256, 256, 0, stream>>>(w_out, woH, woL);
    init_kernel<<<1, 64, 0, stream>>>(bar);

    GruP p;
    p.hseq = hseq; p.table = table;
    p.whhH = whhH; p.whhL = whhL; p.wihH = wihH; p.wihL = wihL;
    p.woH = woH; p.woL = woL;
    p.b_hh = b_hh; p.b_out = b_out;
    p.out = out; p.gbufA = gbufA; p.gbufB = gbufB; p.bar = bar;

    void* args[] = { &p };
    hipError_t e = hipLaunchCooperativeKernel((void*)gru_persist,
                                              dim3(256), dim3(512), args, 0, stream);
    if (e != hipSuccess) {
        // 256 blocks x 1/CU on 256 CUs: plain launch is co-resident in practice
        gru_persist<<<256, 512, 0, stream>>>(p);
    }
}

// Round 13
// 50667.899 us; speedup vs baseline: 1.6326x; 1.0463x over previous
//
#include <hip/hip_runtime.h>
#include <math.h>

#define NLFULL 504
#define REAL_NL 500
#define BATCH 2048
#define NZ 50
#define NC 21
#define GHID 512
#define EPSB 1e-5f
#define LO_SCALE 2048.0f
#define INV_LO (1.0f / 2048.0f)

typedef __attribute__((ext_vector_type(4))) float f32x4;
typedef __attribute__((ext_vector_type(8))) _Float16 half8;

__device__ __forceinline__ void split2(float x, _Float16& hi, _Float16& lo) {
    hi = (_Float16)x;
    lo = (_Float16)((x - (float)hi) * LO_SCALE);
}
__device__ __forceinline__ unsigned packh(float x) {
    _Float16 hi, lo; split2(x, hi, lo);
    return (unsigned)__builtin_bit_cast(unsigned short, hi)
         | ((unsigned)__builtin_bit_cast(unsigned short, lo) << 16);
}

// =============================== upsample ==================================
__global__ __launch_bounds__(512) void upsample_kernel(
    const float* __restrict__ z, const float* __restrict__ dW, const float* __restrict__ db,
    const float* __restrict__ W0, const float* __restrict__ g0, const float* __restrict__ bb0,
    const float* __restrict__ m0, const float* __restrict__ v0, const float* __restrict__ al0,
    const float* __restrict__ W1, const float* __restrict__ g1, const float* __restrict__ bb1,
    const float* __restrict__ m1, const float* __restrict__ v1, const float* __restrict__ al1,
    const float* __restrict__ W2, const float* __restrict__ g2, const float* __restrict__ bb2,
    const float* __restrict__ m2, const float* __restrict__ v2, const float* __restrict__ al2,
    float* __restrict__ hseq)
{
    __shared__ float bufA[5712];
    __shared__ float bufB[5544];
    __shared__ float zl[52];

    const int b   = blockIdx.x;
    const int ta  = blockIdx.y * 16;
    const int nt0 = min(16, 63 - ta);
    const int tid = threadIdx.x;

    if (tid < NZ) zl[tid] = z[b * NZ + tid];
    __syncthreads();

    for (int i = tid; i < 336 * nt0; i += 512) {
        int c = i % 336, tt = i / 336;
        int row = c * 63 + ta + tt;
        const float* wr = dW + (size_t)row * NZ;
        float s = db[row];
        #pragma unroll
        for (int n = 0; n < NZ; ++n) s += zl[n] * wr[n];
        bufA[c * 17 + tt] = s;
    }
    __syncthreads();

    const float a0 = al0[0], a1 = al1[0], a2 = al2[0];

    for (int i = tid; i < 168 * 2 * nt0; i += 512) {
        int o = i % 168, tt1 = i / 168;
        int tt = tt1 >> 1, k = tt1 & 1;
        const float* wp = W0 + o * 2 + k;
        float s = 0.f;
        for (int c = 0; c < 336; ++c) s += bufA[c * 17 + tt] * wp[c * 336];
        float sc = g0[o] / sqrtf(v0[o] + EPSB);
        s = (s - m0[o]) * sc + bb0[o];
        s = (s >= 0.f) ? s : a0 * s;
        bufB[o * 33 + tt1] = s;
    }
    __syncthreads();

    for (int i = tid; i < 84 * 4 * nt0; i += 512) {
        int o = i % 84, tt2 = i / 84;
        int tt1 = tt2 >> 1, k = tt2 & 1;
        const float* wp = W1 + o * 2 + k;
        float s = 0.f;
        for (int c = 0; c < 168; ++c) s += bufB[c * 33 + tt1] * wp[c * 168];
        float sc = g1[o] / sqrtf(v1[o] + EPSB);
        s = (s - m1[o]) * sc + bb1[o];
        s = (s >= 0.f) ? s : a1 * s;
        bufA[o * 65 + tt2] = s;
    }
    __syncthreads();

    for (int i = tid; i < 42 * 8 * nt0; i += 512) {
        int o = i % 42, tt3 = i / 42;
        int tt2 = tt3 >> 1, k = tt3 & 1;
        const float* wp = W2 + o * 2 + k;
        float s = 0.f;
        for (int c = 0; c < 84; ++c) s += bufA[c * 65 + tt2] * wp[c * 84];
        float sc = g2[o] / sqrtf(v2[o] + EPSB);
        s = (s - m2[o]) * sc + bb2[o];
        s = (s >= 0.f) ? s : a2 * s;
        int t3 = 8 * ta + tt3;
        hseq[(size_t)t3 * (BATCH * 42) + b * 42 + o] = s;
    }
}

// ================= table: gi-contribution of one-hot px =====================
__global__ void table_kernel(const float* __restrict__ w_px, const float* __restrict__ b_px,
                             const float* __restrict__ w_ih, const float* __restrict__ b_ih,
                             float* __restrict__ table)
{
    int i = blockIdx.x * 256 + threadIdx.x;
    if (i >= 22 * 1536) return;
    int e = i / 1536, jg = i % 1536;
    const float* wih = w_ih + jg * 63 + 42;
    float s = b_ih[jg];
    #pragma unroll
    for (int jp = 0; jp < NC; ++jp) {
        float px = b_px[jp] + (e < NC ? w_px[jp * NC + e] : 0.f);
        s += px * wih[jp];
    }
    table[i] = s;
}

// ====== pack weights into MFMA B-fragment order, fp16 2-limb (lo x2048) =====
__global__ void pack_whh_kernel(const float* __restrict__ w_hh,
                                _Float16* __restrict__ pH, _Float16* __restrict__ pL)
{
    int i = blockIdx.x * 256 + threadIdx.x;
    if (i >= 3 * 32 * 16 * 512) return;
    int e = i & 7, l = (i >> 3) & 63, kf = (i >> 9) & 15, nf = (i >> 13) & 31, g = i >> 18;
    int n = nf * 16 + (l & 15);
    int k = kf * 32 + ((l >> 4) << 3) + e;
    float v = w_hh[(size_t)(g * GHID + n) * GHID + k];
    _Float16 hi, lo; split2(v, hi, lo);
    pH[i] = hi; pL[i] = lo;
}

__global__ void pack_wih_kernel(const float* __restrict__ w_ih,
                                _Float16* __restrict__ pH, _Float16* __restrict__ pL)
{
    int i = blockIdx.x * 256 + threadIdx.x;
    if (i >= 3 * 32 * 2 * 512) return;
    int e = i & 7, l = (i >> 3) & 63, kf = (i >> 9) & 1, nf = (i >> 10) & 31, g = i >> 15;
    int n = nf * 16 + (l & 15);
    int k = kf * 32 + ((l >> 4) << 3) + e;
    float v = (k < 42) ? w_ih[(size_t)(g * GHID + n) * 63 + k] : 0.f;
    _Float16 hi, lo; split2(v, hi, lo);
    pH[i] = hi; pL[i] = lo;
}

__global__ void pack_wout_kernel(const float* __restrict__ w_out,
                                 _Float16* __restrict__ pH, _Float16* __restrict__ pL)
{
    int i = blockIdx.x * 256 + threadIdx.x;
    if (i >= 2 * 16 * 512) return;
    int e = i & 7, l = (i >> 3) & 63, kf = (i >> 9) & 15, nf = i >> 13;
    int n = nf * 16 + (l & 15);
    int k = kf * 32 + ((l >> 4) << 3) + e;
    float v = (n < NC) ? w_out[(size_t)n * GHID + k] : 0.f;
    _Float16 hi, lo; split2(v, hi, lo);
    pH[i] = hi; pL[i] = lo;
}

// =========================== init barrier ===================================
__global__ void init_kernel(int* __restrict__ bar)
{
    if (blockIdx.x == 0 && threadIdx.x < 64) bar[threadIdx.x] = 0;
}

// ================ persistent column-split decode ============================
// 256 blocks x 512 thr, 1/CU (LDS 137 KB), cooperative. bid&7 = col-slice =
// XCD -> per-XCD weight slice ~0.7 MB L2-RESIDENT. bid>>3 = row-group (64
// rows). Full-width h[64][512] in LDS (2-limb fp16, XOR-swizzled). Per step:
// gates (LDS-A x L2-B) -> coalesced agent-atomic u32 stores of h_new ->
// global barrier (release add + RELAXED spin; NO acquire — an agent-scope
// acquire emits buffer_inv per poll and destroys the L2 weight residency,
// r12's 69 MB/step refetch) -> copy phase (8B relaxed agent-atomic loads ->
// LDS: these read the LLC coherence point directly, so no invalidate is
// needed for visibility; proven correct in r7) -> logits from LDS -> argmax.
#define MFMA3(mainA, crossA, aH_, aL_, bH_, bL_) do {                              \
    mainA  = __builtin_amdgcn_mfma_f32_16x16x32_f16(aH_, bH_, mainA, 0, 0, 0);     \
    crossA = __builtin_amdgcn_mfma_f32_16x16x32_f16(aH_, bL_, crossA, 0, 0, 0);    \
    crossA = __builtin_amdgcn_mfma_f32_16x16x32_f16(aL_, bH_, crossA, 0, 0, 0);    \
} while (0)

struct GruP {
    const float* hseq;
    const float* table;
    const _Float16 *whhH, *whhL, *wihH, *wihL, *woH, *woL;
    const float *b_hh, *b_out;
    float* out;
    unsigned *gbufA, *gbufB;
    int* bar;
};

__global__ __launch_bounds__(512, 2) void gru_persist(GruP p)
{
    __shared__ _Float16 hH[64 * 512];     // 64 KB, swizzled elem^=(row&7)<<3
    __shared__ _Float16 hL[64 * 512];     // 64 KB
    __shared__ float    lg[64][33];       // 8.4 KB
    __shared__ int      idx_l[64];

    const int bid = blockIdx.x;
    const int cb  = bid & 7;              // col-slice == XCD heuristic
    const int rb  = bid >> 3;             // row-group 0..31
    const int row0 = rb * 64;
    const int tid = threadIdx.x;
    const int l   = tid & 63, wv = tid >> 6;
    const int lrow = l & 15, lk = (l >> 4) << 3;

    const int mi2 = wv >> 2;              // 0..1 : two 16-row A-frags each
    const int nfl = wv & 3;               // 0..3 : local n-frag
    const int nfg = cb * 4 + nfl;         // global n-frag 0..31
    const int c   = nfg * 16 + lrow;      // this lane's output column

    // ---- prologue: h[-1] = 0, idx = NC -------------------------------------
    for (int i = tid; i < 64 * 512; i += 512) { hH[i] = (_Float16)0.f; hL[i] = (_Float16)0.f; }
    if (tid < 64) idx_l[tid] = NC;
    __syncthreads();

    const float bhr = p.b_hh[c], bhz = p.b_hh[GHID + c], bhn = p.b_hh[2 * GHID + c];

    for (int t = 0; t < REAL_NL; ++t) {
        unsigned* gbuf = (t & 1) ? p.gbufB : p.gbufA;
        const float* ht = p.hseq + (size_t)t * (BATCH * 42);

        // ---------------- gates: h[t] from LDS h[t-1] ------------------------
        {
            // streams: 0=r 1=z 2=in(I) 3=hn(H); [stream][mi]
            f32x4 gM[4][2], gX[4][2];
            #pragma unroll
            for (int s = 0; s < 4; ++s) {
                #pragma unroll
                for (int mi = 0; mi < 2; ++mi) { gM[s][mi] = (f32x4)0.f; gX[s][mi] = (f32x4)0.f; }
            }

            for (int kf = 0; kf < 16; ++kf) {
                half8 aH[2], aL[2];
                #pragma unroll
                for (int mi = 0; mi < 2; ++mi) {
                    int lm = (mi2 * 2 + mi) * 16 + lrow;
                    int ao = lm * 512 + ((kf * 32 + lk) ^ ((lm & 7) << 3));
                    aH[mi] = *(const half8*)(&hH[ao]);
                    aL[mi] = *(const half8*)(&hL[ao]);
                }
                #pragma unroll
                for (int g = 0; g < 3; ++g) {
                    size_t bo = ((size_t)((g * 32 + nfg) * 16 + kf) << 9) + (l << 3);
                    half8 bH = *(const half8*)(p.whhH + bo);
                    half8 bL = *(const half8*)(p.whhL + bo);
                    const int s = (g == 2) ? 3 : g;
                    #pragma unroll
                    for (int mi = 0; mi < 2; ++mi) {
                        MFMA3(gM[s][mi], gX[s][mi], aH[mi], aL[mi], bH, bL);
                    }
                }
            }
            // I part: K = 42 (plain cached loads, on-the-fly split)
            #pragma unroll
            for (int kf = 0; kf < 2; ++kf) {
                half8 aH[2], aL[2];
                #pragma unroll
                for (int mi = 0; mi < 2; ++mi) {
                    const float* rp = ht + (size_t)(row0 + (mi2 * 2 + mi) * 16 + lrow) * 42;
                    #pragma unroll
                    for (int e = 0; e < 8; ++e) {
                        int k = kf * 32 + lk + e;
                        float f = (k < 42) ? rp[k] : 0.f;
                        _Float16 hi, lo; split2(f, hi, lo);
                        aH[mi][e] = hi; aL[mi][e] = lo;
                    }
                }
                #pragma unroll
                for (int g = 0; g < 3; ++g) {
                    size_t bo = ((size_t)((g * 32 + nfg) * 2 + kf) << 9) + (l << 3);
                    half8 bH = *(const half8*)(p.wihH + bo);
                    half8 bL = *(const half8*)(p.wihL + bo);
                    const int s = (g == 2) ? 2 : g;
                    #pragma unroll
                    for (int mi = 0; mi < 2; ++mi) {
                        MFMA3(gM[s][mi], gX[s][mi], aH[mi], aL[mi], bH, bL);
                    }
                }
            }

            // epilogue: D row=(l>>4)*4+r, col=l&15; coalesced atomic u32 stores
            #pragma unroll
            for (int mi = 0; mi < 2; ++mi) {
                #pragma unroll
                for (int r = 0; r < 4; ++r) {
                    int lm = (mi2 * 2 + mi) * 16 + ((l >> 4) << 2) + r;
                    const float* tb = p.table + idx_l[lm] * 1536;
                    float rv  = gM[0][mi][r] + gX[0][mi][r] * INV_LO + bhr + tb[c];
                    float zv  = gM[1][mi][r] + gX[1][mi][r] * INV_LO + bhz + tb[GHID + c];
                    float inp = gM[2][mi][r] + gX[2][mi][r] * INV_LO + tb[2 * GHID + c];
                    float hnp = gM[3][mi][r] + gX[3][mi][r] * INV_LO + bhn;
                    float rg = 1.f / (1.f + expf(-rv));
                    float zg = 1.f / (1.f + expf(-zv));
                    float ng = tanhf(inp + rg * hnp);
                    int ho = lm * 512 + (c ^ ((lm & 7) << 3));
                    float hpv = (float)hH[ho] + (float)hL[ho] * INV_LO;
                    float hnv = (1.f - zg) * ng + zg * hpv;
                    __hip_atomic_store(gbuf + (size_t)(row0 + lm) * 512 + c, packh(hnv),
                                       __ATOMIC_RELAXED, __HIP_MEMORY_SCOPE_AGENT);
                }
            }
        }

        // ---------------- global barrier (release add, RELAXED spin) ---------
        __syncthreads();
        if (tid == 0) {
            __hip_atomic_fetch_add(p.bar, 1, __ATOMIC_RELEASE, __HIP_MEMORY_SCOPE_AGENT);
            int target = (t + 1) * 256;
            while (__hip_atomic_load(p.bar, __ATOMIC_RELAXED, __HIP_MEMORY_SCOPE_AGENT) < target)
                __builtin_amdgcn_s_sleep(2);
        }
        __syncthreads();

        // ---------------- copy phase: gbuf -> LDS (coherent loads) -----------
        {
            const unsigned long long* src =
                (const unsigned long long*)(gbuf + (size_t)row0 * 512);
            for (int i = tid; i < 64 * 256; i += 512) {     // 32 iters of 8B
                unsigned long long d = __hip_atomic_load(
                    (unsigned long long*)(src + i), __ATOMIC_RELAXED, __HIP_MEMORY_SCOPE_AGENT);
                int e = i * 2;
                int r = e >> 9, cc = e & 511;               // cc even
                unsigned w0 = (unsigned)d, w1 = (unsigned)(d >> 32);
                int o = r * 512 + (cc ^ ((r & 7) << 3));
                *(unsigned*)&hH[o] = (w0 & 0xFFFFu) | (w1 << 16);
                *(unsigned*)&hL[o] = (w0 >> 16) | (w1 & 0xFFFF0000u);
            }
        }
        __syncthreads();

        // ---------------- logits from LDS h[t] -------------------------------
        {
            const int lmi = wv >> 1, wnf = wv & 1;
            f32x4 lM = (f32x4)0.f, lX = (f32x4)0.f;
            for (int kf = 0; kf < 16; ++kf) {
                int lm = lmi * 16 + lrow;
                int ao = lm * 512 + ((kf * 32 + lk) ^ ((lm & 7) << 3));
                half8 aH = *(const half8*)(&hH[ao]);
                half8 aL = *(const half8*)(&hL[ao]);
                size_t bo = ((size_t)(wnf * 16 + kf) << 9) + (l << 3);
                half8 bH = *(const half8*)(p.woH + bo);
                half8 bL = *(const half8*)(p.woL + bo);
                MFMA3(lM, lX, aH, aL, bH, bL);
            }
            int col = wnf * 16 + lrow;
            float bias = (col < NC) ? p.b_out[col] : 0.f;
            #pragma unroll
            for (int r = 0; r < 4; ++r)
                lg[lmi * 16 + ((l >> 4) << 2) + r][col] = lM[r] + lX[r] * INV_LO + bias;
        }
        __syncthreads();

        // ---------------- argmax (first-max) + out[t] -------------------------
        if (tid < 64) {
            float best = lg[tid][0]; int bi = 0;
            #pragma unroll
            for (int cc2 = 1; cc2 < NC; ++cc2) {
                float v = lg[tid][cc2];
                if (v > best) { best = v; bi = cc2; }   // strict > keeps first max
            }
            idx_l[tid] = bi;
            if (cb == 0) {
                float* op = p.out + (size_t)(row0 + tid) * (REAL_NL * NC) + (size_t)t * NC;
                #pragma unroll
                for (int cc2 = 0; cc2 < NC; ++cc2) op[cc2] = lg[tid][cc2];
            }
        }
        __syncthreads();
    }
}

// ============================================================================
extern "C" void kernel_launch(void* const* d_in, const int* in_sizes, int n_in,
                              void* d_out, int out_size, void* d_ws, size_t ws_size,
                              hipStream_t stream)
{
    const float* z    = (const float*)d_in[1];
    const float* dW   = (const float*)d_in[3];
    const float* db   = (const float*)d_in[4];
    const float* W0   = (const float*)d_in[5];
    const float* g0   = (const float*)d_in[6];
    const float* bb0  = (const float*)d_in[7];
    const float* m0   = (const float*)d_in[8];
    const float* v0   = (const float*)d_in[9];
    const float* al0  = (const float*)d_in[10];
    const float* W1   = (const float*)d_in[11];
    const float* g1   = (const float*)d_in[12];
    const float* bb1  = (const float*)d_in[13];
    const float* m1   = (const float*)d_in[14];
    const float* v1   = (const float*)d_in[15];
    const float* al1  = (const float*)d_in[16];
    const float* W2   = (const float*)d_in[17];
    const float* g2   = (const float*)d_in[18];
    const float* bb2  = (const float*)d_in[19];
    const float* m2   = (const float*)d_in[20];
    const float* v2   = (const float*)d_in[21];
    const float* al2  = (const float*)d_in[22];
    const float* w_px = (const float*)d_in[23];
    const float* b_px = (const float*)d_in[24];
    const float* w_ih = (const float*)d_in[25];
    const float* w_hh = (const float*)d_in[26];
    const float* b_ih = (const float*)d_in[27];
    const float* b_hh = (const float*)d_in[28];
    const float* w_out= (const float*)d_in[29];
    const float* b_out= (const float*)d_in[30];
    float* out = (float*)d_out;

    // ws: hseq(f32) | whh H/L | wih H/L | wo H/L | table | gbufA | gbufB | bar
    float* ws = (float*)d_ws;
    float* hseq = ws;                                            // 504*2048*42 f32
    _Float16* whhH = (_Float16*)(hseq + (size_t)NLFULL * BATCH * 42);
    _Float16* whhL = whhH + 3 * 32 * 16 * 512;
    _Float16* wihH = whhL + 3 * 32 * 16 * 512;
    _Float16* wihL = wihH + 3 * 32 * 2 * 512;
    _Float16* woH  = wihL + 3 * 32 * 2 * 512;
    _Float16* woL  = woH + 2 * 16 * 512;
    float* table   = (float*)(woL + 2 * 16 * 512);               // 22*1536
    unsigned* gbufA = (unsigned*)(table + 22 * 1536);            // 2048*512 u32
    unsigned* gbufB = gbufA + (size_t)BATCH * GHID;
    int* bar       = (int*)(gbufB + (size_t)BATCH * GHID);       // 64

    upsample_kernel<<<dim3(BATCH, 4), 512, 0, stream>>>(
        z, dW, db,
        W0, g0, bb0, m0, v0, al0,
        W1, g1, bb1, m1, v1, al1,
        W2, g2, bb2, m2, v2, al2,
        hseq);

    table_kernel<<<(22 * 1536 + 255) / 256, 256, 0, stream>>>(w_px, b_px, w_ih, b_ih, table);
    pack_whh_kernel<<<(3 * 32 * 16 * 512 + 255) / 256, 256, 0, stream>>>(w_hh, whhH, whhL);
    pack_wih_kernel<<<(3 * 32 * 2 * 512 + 255) / 256, 256, 0, stream>>>(w_ih, wihH, wihL);
    pack_wout_kernel<<<(2 * 16 * 512 + 255) / 256, 256, 0, stream>>>(w_out, woH, woL);
    init_kernel<<<1, 64, 0, stream>>>(bar);

    GruP p;
    p.hseq = hseq; p.table = table;
    p.whhH = whhH; p.whhL = whhL; p.wihH = wihH; p.wihL = wihL;
    p.woH = woH; p.woL = woL;
    p.b_hh = b_hh; p.b_out = b_out;
    p.out = out; p.gbufA = gbufA; p.gbufB = gbufB; p.bar = bar;

    void* args[] = { &p };
    hipError_t e = hipLaunchCooperativeKernel((void*)gru_persist,
                                              dim3(256), dim3(512), args, 0, stream);
    if (e != hipSuccess) {
        // 256 blocks x 1/CU on 256 CUs: plain launch is co-resident in practice
        gru_persist<<<256, 512, 0, stream>>>(p);
    }
}